// Round 3
// baseline (2874.522 us; speedup 1.0000x reference)
//
#include <hip/hip_runtime.h>
#include <hip/hip_fp16.h>

// APPNP encoder: e3 = ego + 0.9*A@(ego + 0.9*A@ego).
// R11: seg-locality WITHOUT fragmentation. R10 proved seg-tiling cuts L2-miss
// traffic to ~the 8-XCD floor (191->93MB) but its tiny (seg,row) bins killed
// the unrolled gather pipeline (dynamic rem loop -> serial loads -> 2x slower).
// R11 sorts each bucket's edges by SEGMENT ONLY (7 bins of ~585 edges), keeps
// the fully-unrolled 16-deep chunk loop from R9 (16 gathers in flight), and
// routes the now-dynamic row via LDS f32 accumulators (ds_add_f32) instead of
// per-row registers. Seg order is only a locality hint; chunks may straddle
// segments safely. Both SpMM passes use the structure.
//  1. conv_init: fp32 ego -> fp16 table; init padded bucket cursors
//  2. bucket_scatter (512t): single-pass scatter into padded bucket slots
//  3. sort_spmm1 (512t): reg-held 7-bin seg sort -> ebuf, then chunked
//     seg-major SpMM into LDS acc, writeout e2 = acc + ego (fp16)
//  4. spmm2 (512t): same chunked SpMM from e2h, writeout out = acc + ego (f32)

#define USER_NUM 60000
#define ITEM_NUM 40000
#define N_NODES  100000
#define EMB      64
#define NNZ      3200000
#define OMA       0.9f   // 1 - alpha
#define BR       128     // rows per bucket
#define NB       782     // ceil(100000/128)
#define TILE     4096    // edges per scatter block
#define CAPB     4480    // padded slots per bucket (mean 4096, +6 sigma)
#define SEG_SHIFT 14     // 16384 cols/segment = 2MB of fp16 table (fits XCD L2)
#define NSEG     7       // ceil(100000/16384)
#define AST      68      // acc row stride in floats: 272B = 16B-aligned, bank shift 4

typedef float f32x4 __attribute__((ext_vector_type(4)));

// ---- 1) fp32 split ego -> flat fp16 table; init bucket cursors ----------
__global__ __launch_bounds__(256) void conv_init(const float* __restrict__ ue,
                                                 const float* __restrict__ ie,
                                                 __half* __restrict__ dst,
                                                 int* __restrict__ bcursor) {
    int t = blockIdx.x * 256 + threadIdx.x;       // 8 floats per thread
    if (t < NB) bcursor[t] = t * CAPB;
    const int total8 = N_NODES * EMB / 8;         // 800,000
    if (t >= total8) return;
    size_t f0 = (size_t)t * 8;
    const size_t usz = (size_t)USER_NUM * EMB;    // 3,840,000 (mult of 8)
    const float4* s4 = (f0 < usz) ? (const float4*)(ue + f0)
                                  : (const float4*)(ie + (f0 - usz));
    float4 x = s4[0], y = s4[1];
    union { float4 f4; __half2 h2[4]; } o;
    o.h2[0] = __floats2half2_rn(x.x, x.y);
    o.h2[1] = __floats2half2_rn(x.z, x.w);
    o.h2[2] = __floats2half2_rn(y.x, y.y);
    o.h2[3] = __floats2half2_rn(y.z, y.w);
    ((float4*)dst)[t] = o.f4;
}

// ---- 2) single-pass bucket scatter into padded slots (512 threads) ------
// entry = (col | row_local<<17, val*0.9)
__global__ __launch_bounds__(512) void bucket_scatter(const int* __restrict__ rows,
                                                      const int* __restrict__ cols,
                                                      const float* __restrict__ vals,
                                                      int* __restrict__ bcursor,
                                                      int2* __restrict__ ebuf) {
    __shared__ int bins[NB + 1];   // hist, then exclusive offsets
    __shared__ int lcur[NB];       // binning cursors, then global write offsets
    __shared__ int wsum[8];
    __shared__ int2 stage[TILE];
    int t = threadIdx.x;
    int lane = t & 63, w = t >> 6;           // 8 waves
    for (int b = t; b <= NB; b += 512) bins[b] = 0;
    __syncthreads();

    // load edges, histogram into bins (8 edges/thread)
    int e0 = blockIdx.x * TILE;
    int mybk[8], mypk[8];
    float myv[8];
#pragma unroll
    for (int j = 0; j < 8; ++j) {
        int i = e0 + t + 512 * j;
        mybk[j] = -1;
        if (i < NNZ) {
            int r = rows[i], c = cols[i];
            myv[j]  = vals[i] * OMA;
            mybk[j] = r >> 7;
            mypk[j] = c | ((r & 127) << 17);
            atomicAdd(&bins[mybk[j]], 1);
        }
    }
    __syncthreads();

    // register scan: 2 bins/thread, wave shfl scan + cross-wave combine
    int b0 = t * 2;
    int r0 = (b0     < NB) ? bins[b0]     : 0;
    int r1 = (b0 + 1 < NB) ? bins[b0 + 1] : 0;
    int s = r0 + r1;
    int incl = s;
#pragma unroll
    for (int off = 1; off < 64; off <<= 1) {
        int v = __shfl_up(incl, off, 64);
        if (lane >= off) incl += v;
    }
    if (lane == 63) wsum[w] = incl;
    __syncthreads();
    int prefix = 0;
#pragma unroll
    for (int i = 0; i < 8; ++i) if (i < w) prefix += wsum[i];
    int excl = prefix + incl - s;
    if (b0     < NB) { bins[b0]     = excl; lcur[b0]     = excl; excl += r0; }
    if (b0 + 1 < NB) { bins[b0 + 1] = excl; lcur[b0 + 1] = excl; }
    if (t == 511) bins[NB] = prefix + incl;   // total valid edges this tile
    __syncthreads();

    // bin into stage (bucket-sorted order)
#pragma unroll
    for (int j = 0; j < 8; ++j) {
        if (mybk[j] >= 0) {
            int p = atomicAdd(&lcur[mybk[j]], 1);
            stage[p] = make_int2(mypk[j], __float_as_int(myv[j]));
        }
    }
    __syncthreads();

    // Phase A: reserve global runs; lcur[b] := global_base - local_start
    for (int b = t; b < NB; b += 512) {
        int st = bins[b], en = bins[b + 1];
        int cnt = en - st;
        if (cnt > 0) lcur[b] = atomicAdd(&bcursor[b], cnt) - st;
    }
    __syncthreads();

    // Phase B: lane-parallel coalesced flush (binary search bucket of entry i)
    int total = bins[NB];
    for (int i = t; i < total; i += 512) {
        int lo = 0, hi = NB;
        while (hi - lo > 1) {
            int mid = (lo + hi) >> 1;
            if (bins[mid] <= i) lo = mid; else hi = mid;
        }
        ebuf[(size_t)(lcur[lo] + i)] = stage[i];
    }
}

// ---- 3) reg-held seg sort + chunked LDS-acc spmm1 (512 threads) ---------
__global__ __launch_bounds__(512) void sort_spmm1(const int* __restrict__ bcursor,
                                                  int2* __restrict__ ebuf,
                                                  const __half* __restrict__ ego_h,
                                                  const float* __restrict__ ue,
                                                  const float* __restrict__ ie,
                                                  __half* __restrict__ e2h) {
    __shared__ float acc[BR * AST];               // 34,816 B
    __shared__ int wh[8][8];                      // per-wave seg hist -> prefix
    __shared__ int wcur[8][8];                    // per-wave place cursors
    __shared__ int segtot[NSEG], segofs[NSEG];
    int bk = blockIdx.x, t = threadIdx.x;
    int w = t >> 6;
    int s = bk * CAPB;
    int cnt = min(bcursor[bk] - s, CAPB);

    for (int i = t; i < BR * AST; i += 512) acc[i] = 0.f;
    if (t < 64) wh[t >> 3][t & 7] = 0;
    __syncthreads();

    // (a) load edges into registers + per-wave seg histogram
    int2 ev[8]; int eseg[8];
#pragma unroll
    for (int j = 0; j < 8; ++j) {
        int i = t + 512 * j;
        eseg[j] = -1;
        if (i < cnt) {
            ev[j] = ebuf[(size_t)(s + i)];
            eseg[j] = (ev[j].x & 0x1FFFF) >> SEG_SHIFT;
            atomicAdd(&wh[w][eseg[j]], 1);
        }
    }
    __syncthreads();
    // (b) scan: per-seg prefix over waves, then seg offsets
    if (t < NSEG) {
        int c = 0;
#pragma unroll
        for (int w2 = 0; w2 < 8; ++w2) { int h = wh[w2][t]; wh[w2][t] = c; c += h; }
        segtot[t] = c;
    }
    __syncthreads();
    if (t == 0) { int o = 0; for (int g = 0; g < NSEG; ++g) { segofs[g] = o; o += segtot[g]; } }
    __syncthreads();
    if (t < 64) { int w2 = t >> 3, g = t & 7; if (g < NSEG) wcur[w2][g] = segofs[g] + wh[w2][g]; }
    __syncthreads();
    // (c) place sorted-by-seg back to ebuf (reads all done in (a) -> safe)
#pragma unroll
    for (int j = 0; j < 8; ++j) {
        if (eseg[j] >= 0) {
            int p = atomicAdd(&wcur[w][eseg[j]], 1);
            ebuf[(size_t)(s + p)] = ev[j];
        }
    }
    __syncthreads();   // drains stores to L2 before re-read

    // (d) chunked seg-major SpMM: 32 groups x 16 lanes, full unroll 16,
    //     dynamic row -> LDS f32 atomic accumulate
    int lane  = t & 15;
    int qbase = (t & 63) & ~15;
    int gg = t >> 4;                              // 0..31
    const float2* srcv = (const float2*)ego_h;
    const unsigned long long* eb8 = (const unsigned long long*)ebuf;
    for (int c0 = gg; c0 * 16 < cnt; c0 += 32) {
        int base = c0 * 16;
        int nv = cnt - base;                      // >= 1
        unsigned long long pv = 0;
        if (lane < nv)
            pv = __hip_atomic_load(eb8 + (size_t)(s + base + lane),
                                   __ATOMIC_RELAXED, __HIP_MEMORY_SCOPE_AGENT);
        int cx = (int)(pv & 0xFFFFFFFFull), cyv = (int)(pv >> 32);
        if (nv >= 16) {
#pragma unroll
            for (int j = 0; j < 16; ++j) {
                int   pk = __shfl(cx, qbase + j, 64);
                float vj = __int_as_float(__shfl(cyv, qbase + j, 64));
                int cj  = pk & 0x1FFFF;
                int row = (pk >> 17) & 127;
                union { float2 f2; __half2 h2[2]; } u;
                u.f2 = srcv[(size_t)cj * 16 + lane];
                float2 a = __half22float2(u.h2[0]);
                float2 b = __half22float2(u.h2[1]);
                int ab = row * AST + lane * 4;
                atomicAdd(&acc[ab + 0], vj * a.x);
                atomicAdd(&acc[ab + 1], vj * a.y);
                atomicAdd(&acc[ab + 2], vj * b.x);
                atomicAdd(&acc[ab + 3], vj * b.y);
            }
        } else {
#pragma unroll
            for (int j = 0; j < 16; ++j) {
                int   pk = __shfl(cx, qbase + j, 64);
                float vj = __int_as_float(__shfl(cyv, qbase + j, 64));
                if (j >= nv) { vj = 0.f; pk = 0; }
                int cj  = pk & 0x1FFFF;
                int row = (pk >> 17) & 127;
                union { float2 f2; __half2 h2[2]; } u;
                u.f2 = srcv[(size_t)cj * 16 + lane];
                float2 a = __half22float2(u.h2[0]);
                float2 b = __half22float2(u.h2[1]);
                int ab = row * AST + lane * 4;
                atomicAdd(&acc[ab + 0], vj * a.x);
                atomicAdd(&acc[ab + 1], vj * a.y);
                atomicAdd(&acc[ab + 2], vj * b.x);
                atomicAdd(&acc[ab + 3], vj * b.y);
            }
        }
    }
    __syncthreads();

    // (e) writeout: e2 = acc + ego -> fp16
#pragma unroll
    for (int q = 0; q < 4; ++q) {
        int fid = t + 512 * q;                    // 0..2047 float4-slots
        int row = fid >> 4, c4 = fid & 15;
        int r = (bk << 7) + row;
        if (r < N_NODES) {
            const float* egop = (r < USER_NUM) ? (ue + (size_t)r * EMB)
                                               : (ie + (size_t)(r - USER_NUM) * EMB);
            float4 e = ((const float4*)egop)[c4];
            float4 m = *(const float4*)&acc[row * AST + c4 * 4];
            union { float2 f2; __half2 h2[2]; } o;
            o.h2[0] = __floats2half2_rn(e.x + m.x, e.y + m.y);
            o.h2[1] = __floats2half2_rn(e.z + m.z, e.w + m.w);
            ((float2*)e2h)[(size_t)r * 16 + c4] = o.f2;
        }
    }
}

// ---- 4) spmm2: chunked LDS-acc pull from e2h, fp32 nt out ---------------
__global__ __launch_bounds__(512) void spmm2(const int* __restrict__ bcursor,
                                             const int2* __restrict__ ebuf,
                                             const __half* __restrict__ src,
                                             const float* __restrict__ ue,
                                             const float* __restrict__ ie,
                                             float* __restrict__ outb) {
    __shared__ float acc[BR * AST];
    int bk = blockIdx.x, t = threadIdx.x;
    int s = bk * CAPB;
    int cnt = min(bcursor[bk] - s, CAPB);
    for (int i = t; i < BR * AST; i += 512) acc[i] = 0.f;
    __syncthreads();

    int lane  = t & 15;
    int qbase = (t & 63) & ~15;
    int gg = t >> 4;
    const float2* srcv = (const float2*)src;
    const unsigned long long* eb8 = (const unsigned long long*)ebuf;
    for (int c0 = gg; c0 * 16 < cnt; c0 += 32) {
        int base = c0 * 16;
        int nv = cnt - base;
        unsigned long long pv = 0;
        if (lane < nv) pv = eb8[(size_t)(s + base + lane)];
        int cx = (int)(pv & 0xFFFFFFFFull), cyv = (int)(pv >> 32);
        if (nv >= 16) {
#pragma unroll
            for (int j = 0; j < 16; ++j) {
                int   pk = __shfl(cx, qbase + j, 64);
                float vj = __int_as_float(__shfl(cyv, qbase + j, 64));
                int cj  = pk & 0x1FFFF;
                int row = (pk >> 17) & 127;
                union { float2 f2; __half2 h2[2]; } u;
                u.f2 = srcv[(size_t)cj * 16 + lane];
                float2 a = __half22float2(u.h2[0]);
                float2 b = __half22float2(u.h2[1]);
                int ab = row * AST + lane * 4;
                atomicAdd(&acc[ab + 0], vj * a.x);
                atomicAdd(&acc[ab + 1], vj * a.y);
                atomicAdd(&acc[ab + 2], vj * b.x);
                atomicAdd(&acc[ab + 3], vj * b.y);
            }
        } else {
#pragma unroll
            for (int j = 0; j < 16; ++j) {
                int   pk = __shfl(cx, qbase + j, 64);
                float vj = __int_as_float(__shfl(cyv, qbase + j, 64));
                if (j >= nv) { vj = 0.f; pk = 0; }
                int cj  = pk & 0x1FFFF;
                int row = (pk >> 17) & 127;
                union { float2 f2; __half2 h2[2]; } u;
                u.f2 = srcv[(size_t)cj * 16 + lane];
                float2 a = __half22float2(u.h2[0]);
                float2 b = __half22float2(u.h2[1]);
                int ab = row * AST + lane * 4;
                atomicAdd(&acc[ab + 0], vj * a.x);
                atomicAdd(&acc[ab + 1], vj * a.y);
                atomicAdd(&acc[ab + 2], vj * b.x);
                atomicAdd(&acc[ab + 3], vj * b.y);
            }
        }
    }
    __syncthreads();

    // writeout: out = acc + ego (f32, nontemporal)
#pragma unroll
    for (int q = 0; q < 4; ++q) {
        int fid = t + 512 * q;
        int row = fid >> 4, c4 = fid & 15;
        int r = (bk << 7) + row;
        if (r < N_NODES) {
            const float* egop = (r < USER_NUM) ? (ue + (size_t)r * EMB)
                                               : (ie + (size_t)(r - USER_NUM) * EMB);
            float4 e = ((const float4*)egop)[c4];
            float4 m = *(const float4*)&acc[row * AST + c4 * 4];
            f32x4 av = { e.x + m.x, e.y + m.y, e.z + m.z, e.w + m.w };
            __builtin_nontemporal_store(av, &((f32x4*)outb)[(size_t)r * 16 + c4]);
        }
    }
}

// ---- launch -------------------------------------------------------------
extern "C" void kernel_launch(void* const* d_in, const int* in_sizes, int n_in,
                              void* d_out, int out_size, void* d_ws, size_t ws_size,
                              hipStream_t stream) {
    const int*   rows = (const int*)d_in[0];
    const int*   cols = (const int*)d_in[1];
    const float* vals = (const float*)d_in[2];
    const float* ue   = (const float*)d_in[3];
    const float* ie   = (const float*)d_in[4];
    float* out = (float*)d_out;

    char* ws = (char*)d_ws;
    __half* ego_h    = (__half*)ws;                   // 12,800,000 B
    __half* e2h      = (__half*)(ws + 12800000);      // 12,800,000 B
    int2*   ebuf     = (int2*)(ws + 25600000);        // 782*4480*8 = 28,026,880 B
    int*    bcursor  = (int*)(ws + 53626880);         // 3,128 B

    const int convBlocks = (N_NODES * EMB / 8 + 255) / 256;  // 3125
    conv_init<<<convBlocks, 256, 0, stream>>>(ue, ie, ego_h, bcursor);

    const int tiles = (NNZ + TILE - 1) / TILE;        // 782
    bucket_scatter<<<tiles, 512, 0, stream>>>(rows, cols, vals, bcursor, ebuf);
    sort_spmm1<<<NB, 512, 0, stream>>>(bcursor, ebuf, ego_h, ue, ie, e2h);
    spmm2<<<NB, 512, 0, stream>>>(bcursor, ebuf, e2h, ue, ie, out);
}

// Round 4
// 284.651 us; speedup vs baseline: 10.0984x; 10.0984x over previous
//
#include <hip/hip_runtime.h>
#include <hip/hip_fp16.h>

// APPNP encoder: e3 = ego + 0.9*A@(ego + 0.9*A@ego).
// R12: (seg,row) bins + always-8 unrolled chunks + 8-lane/16B gather groups.
// Evidence: R10 proved seg-tiling cuts L2-miss traffic 191->93MB (8-XCD
// compulsory floor ~102MB); R11 proved LDS-atomic accumulation is 16x too
// slow (register row-accs required -> row-pure bins); R9 proved tails must
// be zero-filled edges inside a FIXED-trip unrolled body (dynamic j-bound
// serialized loads was R10's real regression). This round combines all three:
// 7 segs (2MB slices), 896 (seg,row) bins/bucket, chunk=8 always-unrolled,
// 8-lane groups loading float4 (8 halves) so per-edge wave-instr cost halves,
// paying for the ~2x chunk-padding/divergence inflation of small bins.
//  1. conv_init: fp32 ego -> fp16 table; init padded bucket cursors
//  2. bucket_scatter (512t): single-pass scatter into padded bucket slots
//  3. sort_spmm1 (512t): (seg,row) counting sort -> rofs_g export, seg-major
//     chunked SpMM with register accs, writes e2 fp16
//  4. spmm2 (512t): same structure from e2h -> fp32 out (nontemporal)

#define USER_NUM 60000
#define ITEM_NUM 40000
#define N_NODES  100000
#define EMB      64
#define NNZ      3200000
#define OMA       0.9f   // 1 - alpha
#define BR       128     // rows per bucket
#define NB       782     // ceil(100000/128)
#define TILE     4096    // edges per scatter block
#define CAPB     4480    // padded slots per bucket (mean 4096, +6 sigma)
#define SEG_SHIFT 14     // 16384 cols/segment = 2MB of fp16 table (fits XCD L2)
#define NSEG     7       // ceil(100000/16384)
#define NBIN     896     // NSEG * BR
#define RG       904     // rofs_g stride per bucket (NBIN+1 rounded to 8)

typedef float f32x4 __attribute__((ext_vector_type(4)));

// ---- 1) fp32 split ego -> flat fp16 table; init bucket cursors ----------
__global__ __launch_bounds__(256) void conv_init(const float* __restrict__ ue,
                                                 const float* __restrict__ ie,
                                                 __half* __restrict__ dst,
                                                 int* __restrict__ bcursor) {
    int t = blockIdx.x * 256 + threadIdx.x;       // 8 floats per thread
    if (t < NB) bcursor[t] = t * CAPB;
    const int total8 = N_NODES * EMB / 8;         // 800,000
    if (t >= total8) return;
    size_t f0 = (size_t)t * 8;
    const size_t usz = (size_t)USER_NUM * EMB;    // 3,840,000 (mult of 8)
    const float4* s4 = (f0 < usz) ? (const float4*)(ue + f0)
                                  : (const float4*)(ie + (f0 - usz));
    float4 x = s4[0], y = s4[1];
    union { float4 f4; __half2 h2[4]; } o;
    o.h2[0] = __floats2half2_rn(x.x, x.y);
    o.h2[1] = __floats2half2_rn(x.z, x.w);
    o.h2[2] = __floats2half2_rn(y.x, y.y);
    o.h2[3] = __floats2half2_rn(y.z, y.w);
    ((float4*)dst)[t] = o.f4;
}

// ---- 2) single-pass bucket scatter into padded slots (512 threads) ------
// entry = (col | row_local<<17, val*0.9)
__global__ __launch_bounds__(512) void bucket_scatter(const int* __restrict__ rows,
                                                      const int* __restrict__ cols,
                                                      const float* __restrict__ vals,
                                                      int* __restrict__ bcursor,
                                                      int2* __restrict__ ebuf) {
    __shared__ int bins[NB + 1];   // hist, then exclusive offsets
    __shared__ int lcur[NB];       // binning cursors, then global write offsets
    __shared__ int wsum[8];
    __shared__ int2 stage[TILE];
    int t = threadIdx.x;
    int lane = t & 63, w = t >> 6;           // 8 waves
    for (int b = t; b <= NB; b += 512) bins[b] = 0;
    __syncthreads();

    // load edges, histogram into bins (8 edges/thread)
    int e0 = blockIdx.x * TILE;
    int mybk[8], mypk[8];
    float myv[8];
#pragma unroll
    for (int j = 0; j < 8; ++j) {
        int i = e0 + t + 512 * j;
        mybk[j] = -1;
        if (i < NNZ) {
            int r = rows[i], c = cols[i];
            myv[j]  = vals[i] * OMA;
            mybk[j] = r >> 7;
            mypk[j] = c | ((r & 127) << 17);
            atomicAdd(&bins[mybk[j]], 1);
        }
    }
    __syncthreads();

    // register scan: 2 bins/thread, wave shfl scan + cross-wave combine
    int b0 = t * 2;
    int r0 = (b0     < NB) ? bins[b0]     : 0;
    int r1 = (b0 + 1 < NB) ? bins[b0 + 1] : 0;
    int s = r0 + r1;
    int incl = s;
#pragma unroll
    for (int off = 1; off < 64; off <<= 1) {
        int v = __shfl_up(incl, off, 64);
        if (lane >= off) incl += v;
    }
    if (lane == 63) wsum[w] = incl;
    __syncthreads();
    int prefix = 0;
#pragma unroll
    for (int i = 0; i < 8; ++i) if (i < w) prefix += wsum[i];
    int excl = prefix + incl - s;
    if (b0     < NB) { bins[b0]     = excl; lcur[b0]     = excl; excl += r0; }
    if (b0 + 1 < NB) { bins[b0 + 1] = excl; lcur[b0 + 1] = excl; }
    if (t == 511) bins[NB] = prefix + incl;   // total valid edges this tile
    __syncthreads();

    // bin into stage (bucket-sorted order)
#pragma unroll
    for (int j = 0; j < 8; ++j) {
        if (mybk[j] >= 0) {
            int p = atomicAdd(&lcur[mybk[j]], 1);
            stage[p] = make_int2(mypk[j], __float_as_int(myv[j]));
        }
    }
    __syncthreads();

    // Phase A: reserve global runs; lcur[b] := global_base - local_start
    for (int b = t; b < NB; b += 512) {
        int st = bins[b], en = bins[b + 1];
        int cnt = en - st;
        if (cnt > 0) lcur[b] = atomicAdd(&bcursor[b], cnt) - st;
    }
    __syncthreads();

    // Phase B: lane-parallel coalesced flush (binary search bucket of entry i)
    int total = bins[NB];
    for (int i = t; i < total; i += 512) {
        int lo = 0, hi = NB;
        while (hi - lo > 1) {
            int mid = (lo + hi) >> 1;
            if (bins[mid] <= i) lo = mid; else hi = mid;
        }
        ebuf[(size_t)(lcur[lo] + i)] = stage[i];
    }
}

// ---- 3) (seg,row) sort + seg-major chunked spmm1 (512 threads) ----------
__global__ __launch_bounds__(512) void sort_spmm1(const int* __restrict__ bcursor,
                                                  int2* __restrict__ ebuf,
                                                  int* __restrict__ rofs_g,
                                                  const __half* __restrict__ ego_h,
                                                  const float* __restrict__ ue,
                                                  const float* __restrict__ ie,
                                                  __half* __restrict__ e2h) {
    __shared__ int2 stage[CAPB];                  // 35,840 B
    __shared__ int rhist[NBIN], rofs[NBIN + 1], rcur[NBIN];
    __shared__ int wsum[8];
    int bk = blockIdx.x, t = threadIdx.x;
    int lane64 = t & 63, w = t >> 6;
    int s = bk * CAPB;
    int cnt = min(bcursor[bk] - s, CAPB);

    for (int i = t; i < NBIN; i += 512) rhist[i] = 0;
    __syncthreads();
    for (int i = t; i < cnt; i += 512) {
        int2 v = ebuf[(size_t)(s + i)];
        stage[i] = v;
        int bin = (((v.x & 0x1FFFF) >> SEG_SHIFT) << 7) | (v.x >> 17);
        atomicAdd(&rhist[bin], 1);
    }
    __syncthreads();
    // 512-thread scan over 896 bins (2/thread): wave shfl scan + combine
    int b0 = t * 2;
    int h0 = (b0     < NBIN) ? rhist[b0]     : 0;
    int h1 = (b0 + 1 < NBIN) ? rhist[b0 + 1] : 0;
    int sum = h0 + h1;
    int incl = sum;
#pragma unroll
    for (int off = 1; off < 64; off <<= 1) {
        int v = __shfl_up(incl, off, 64);
        if (lane64 >= off) incl += v;
    }
    if (lane64 == 63) wsum[w] = incl;
    __syncthreads();
    int prefix = 0;
#pragma unroll
    for (int i = 0; i < 8; ++i) if (i < w) prefix += wsum[i];
    int excl = prefix + incl - sum;
    if (b0     < NBIN) { rofs[b0]     = excl; rcur[b0]     = excl; excl += h0; }
    if (b0 + 1 < NBIN) { rofs[b0 + 1] = excl; rcur[b0 + 1] = excl; }
    if (t == 0) rofs[NBIN] = cnt;
    __syncthreads();

    // write (seg,row)-sorted edges back (L2-local region); export rofs
    for (int i = t; i < cnt; i += 512) {
        int2 v = stage[i];
        int bin = (((v.x & 0x1FFFF) >> SEG_SHIFT) << 7) | (v.x >> 17);
        int p = atomicAdd(&rcur[bin], 1);
        ebuf[(size_t)(s + p)] = v;
    }
    for (int i = t; i <= NBIN; i += 512) rofs_g[bk * RG + i] = rofs[i];
    __syncthreads();   // sorted edges + rofs visible block-wide

    // seg-major chunked SpMM: 64 groups x 8 lanes, 2 rows/group, accs in reg.
    // Chunk = 8 edges, body ALWAYS unrolled x8; OOB lanes carry zero-edges
    // (cj=0, vj=0 -> L1-hot dummy gather, no-op fma).
    int lane  = t & 7;
    int qbase = (t & 63) & ~7;
    int g = t >> 3;                               // 0..63
    int rl0 = g << 1;                             // rows rl0, rl0+1
    const float4* srcv4 = (const float4*)ego_h;
    const unsigned long long* eb8 = (const unsigned long long*)ebuf;
    float4 acc[2][2];
#pragma unroll
    for (int rr = 0; rr < 2; ++rr) {
        int r = (bk << 7) + rl0 + rr;
        acc[rr][0] = make_float4(0.f, 0.f, 0.f, 0.f);
        acc[rr][1] = make_float4(0.f, 0.f, 0.f, 0.f);
        if (r < N_NODES) {
            const float* egop = (r < USER_NUM) ? (ue + (size_t)r * EMB)
                                               : (ie + (size_t)(r - USER_NUM) * EMB);
            acc[rr][0] = ((const float4*)egop)[lane * 2];
            acc[rr][1] = ((const float4*)egop)[lane * 2 + 1];
        }
    }
    for (int seg = 0; seg < NSEG; ++seg) {
#pragma unroll
        for (int rr = 0; rr < 2; ++rr) {
            int bin = (seg << 7) | (rl0 + rr);
            int ss = rofs[bin], ee = rofs[bin + 1];
            for (int k = ss; k < ee; k += 8) {
                unsigned long long pv = 0;
                if (k + lane < ee) pv = eb8[(size_t)(s + k + lane)];
                int cx = (int)(pv & 0xFFFFFFFFull), cy = (int)(pv >> 32);
#pragma unroll
                for (int j = 0; j < 8; ++j) {
                    int   pk = __shfl(cx, qbase + j, 64);
                    float vj = __int_as_float(__shfl(cy, qbase + j, 64));
                    int cj = pk & 0x1FFFF;
                    union { float4 f4; __half2 h2[4]; } u;
                    u.f4 = srcv4[(size_t)cj * 8 + lane];
                    float2 a0 = __half22float2(u.h2[0]);
                    float2 a1 = __half22float2(u.h2[1]);
                    float2 a2 = __half22float2(u.h2[2]);
                    float2 a3 = __half22float2(u.h2[3]);
                    acc[rr][0].x += vj * a0.x; acc[rr][0].y += vj * a0.y;
                    acc[rr][0].z += vj * a1.x; acc[rr][0].w += vj * a1.y;
                    acc[rr][1].x += vj * a2.x; acc[rr][1].y += vj * a2.y;
                    acc[rr][1].z += vj * a3.x; acc[rr][1].w += vj * a3.y;
                }
            }
        }
    }
#pragma unroll
    for (int rr = 0; rr < 2; ++rr) {
        int r = (bk << 7) + rl0 + rr;
        if (r < N_NODES) {
            union { float4 f4; __half2 h2[4]; } o;
            o.h2[0] = __floats2half2_rn(acc[rr][0].x, acc[rr][0].y);
            o.h2[1] = __floats2half2_rn(acc[rr][0].z, acc[rr][0].w);
            o.h2[2] = __floats2half2_rn(acc[rr][1].x, acc[rr][1].y);
            o.h2[3] = __floats2half2_rn(acc[rr][1].z, acc[rr][1].w);
            ((float4*)e2h)[(size_t)r * 8 + lane] = o.f4;
        }
    }
}

// ---- 4) spmm2: seg-major chunked pull from e2h, fp32 nt out -------------
__global__ __launch_bounds__(512) void spmm2(const int* __restrict__ rofs_g,
                                             const int2* __restrict__ ebuf,
                                             const __half* __restrict__ src,
                                             const float* __restrict__ ue,
                                             const float* __restrict__ ie,
                                             float* __restrict__ outb) {
    __shared__ int rofs[NBIN + 1];
    int bk = blockIdx.x, t = threadIdx.x;
    for (int i = t; i <= NBIN; i += 512) rofs[i] = rofs_g[bk * RG + i];
    __syncthreads();
    int s = bk * CAPB;
    int lane  = t & 7;
    int qbase = (t & 63) & ~7;
    int g = t >> 3;
    int rl0 = g << 1;
    const float4* srcv4 = (const float4*)src;
    const unsigned long long* eb8 = (const unsigned long long*)ebuf;
    float4 acc[2][2];
#pragma unroll
    for (int rr = 0; rr < 2; ++rr) {
        int r = (bk << 7) + rl0 + rr;
        acc[rr][0] = make_float4(0.f, 0.f, 0.f, 0.f);
        acc[rr][1] = make_float4(0.f, 0.f, 0.f, 0.f);
        if (r < N_NODES) {
            const float* egop = (r < USER_NUM) ? (ue + (size_t)r * EMB)
                                               : (ie + (size_t)(r - USER_NUM) * EMB);
            acc[rr][0] = ((const float4*)egop)[lane * 2];
            acc[rr][1] = ((const float4*)egop)[lane * 2 + 1];
        }
    }
    for (int seg = 0; seg < NSEG; ++seg) {
#pragma unroll
        for (int rr = 0; rr < 2; ++rr) {
            int bin = (seg << 7) | (rl0 + rr);
            int ss = rofs[bin], ee = rofs[bin + 1];
            for (int k = ss; k < ee; k += 8) {
                unsigned long long pv = 0;
                if (k + lane < ee) pv = eb8[(size_t)(s + k + lane)];
                int cx = (int)(pv & 0xFFFFFFFFull), cy = (int)(pv >> 32);
#pragma unroll
                for (int j = 0; j < 8; ++j) {
                    int   pk = __shfl(cx, qbase + j, 64);
                    float vj = __int_as_float(__shfl(cy, qbase + j, 64));
                    int cj = pk & 0x1FFFF;
                    union { float4 f4; __half2 h2[4]; } u;
                    u.f4 = srcv4[(size_t)cj * 8 + lane];
                    float2 a0 = __half22float2(u.h2[0]);
                    float2 a1 = __half22float2(u.h2[1]);
                    float2 a2 = __half22float2(u.h2[2]);
                    float2 a3 = __half22float2(u.h2[3]);
                    acc[rr][0].x += vj * a0.x; acc[rr][0].y += vj * a0.y;
                    acc[rr][0].z += vj * a1.x; acc[rr][0].w += vj * a1.y;
                    acc[rr][1].x += vj * a2.x; acc[rr][1].y += vj * a2.y;
                    acc[rr][1].z += vj * a3.x; acc[rr][1].w += vj * a3.y;
                }
            }
        }
    }
#pragma unroll
    for (int rr = 0; rr < 2; ++rr) {
        int r = (bk << 7) + rl0 + rr;
        if (r < N_NODES) {
            f32x4 a0 = { acc[rr][0].x, acc[rr][0].y, acc[rr][0].z, acc[rr][0].w };
            f32x4 a1 = { acc[rr][1].x, acc[rr][1].y, acc[rr][1].z, acc[rr][1].w };
            __builtin_nontemporal_store(a0, &((f32x4*)outb)[(size_t)r * 16 + lane * 2]);
            __builtin_nontemporal_store(a1, &((f32x4*)outb)[(size_t)r * 16 + lane * 2 + 1]);
        }
    }
}

// ---- launch -------------------------------------------------------------
extern "C" void kernel_launch(void* const* d_in, const int* in_sizes, int n_in,
                              void* d_out, int out_size, void* d_ws, size_t ws_size,
                              hipStream_t stream) {
    const int*   rows = (const int*)d_in[0];
    const int*   cols = (const int*)d_in[1];
    const float* vals = (const float*)d_in[2];
    const float* ue   = (const float*)d_in[3];
    const float* ie   = (const float*)d_in[4];
    float* out = (float*)d_out;

    char* ws = (char*)d_ws;
    __half* ego_h    = (__half*)ws;                   // 12,800,000 B
    __half* e2h      = (__half*)(ws + 12800000);      // 12,800,000 B
    int2*   ebuf     = (int2*)(ws + 25600000);        // 782*4480*8 = 28,026,880 B
    int*    rofs_g   = (int*)(ws + 53626880);         // 782*904*4 = 2,827,712 B
    int*    bcursor  = (int*)(ws + 56454592);         // 3,128 B

    const int convBlocks = (N_NODES * EMB / 8 + 255) / 256;  // 3125
    conv_init<<<convBlocks, 256, 0, stream>>>(ue, ie, ego_h, bcursor);

    const int tiles = (NNZ + TILE - 1) / TILE;        // 782
    bucket_scatter<<<tiles, 512, 0, stream>>>(rows, cols, vals, bcursor, ebuf);
    sort_spmm1<<<NB, 512, 0, stream>>>(bcursor, ebuf, rofs_g, ego_h, ue, ie, e2h);
    spmm2<<<NB, 512, 0, stream>>>(rofs_g, ebuf, e2h, ue, ie, out);
}

// Round 5
// 279.490 us; speedup vs baseline: 10.2849x; 1.0185x over previous
//
#include <hip/hip_runtime.h>
#include <hip/hip_fp16.h>

// APPNP encoder: e3 = ego + 0.9*A@(ego + 0.9*A@ego).
// R13: R9's proven SpMM structure (row buckets, 16-lane groups, chunk-16
// unrolled gathers: both SpMM passes sit at the measured ~4.6 TB/s random-
// line delivery wall, 85.8us each) + scatter fix: Phase-B flush previously
// binary-searched the bucket of each staged edge (10 dependent LDS reads x
// 3.2M edges ~= 50us); now the bucket id is recorded in a u16 LDS array at
// binning time and read directly. Evidence trail: R9 occupancy-doubling null
// (latency not the limit), R10/R12 seg-tiling cuts FETCH 191->126MB but
// delivered line rate pins at ~4.6 TB/s regardless -> SpMMs are at a
// transaction-rate roofline; remaining recoverable time is in the scatter.
//  1. conv_init: fp32 ego -> fp16 table; init padded bucket cursors
//  2. bucket_scatter (512t): single-pass scatter, direct bucket-id flush
//  3. sort_spmm1 (512t): per-bucket LDS counting sort -> row_start/row_end +
//     sorted ebuf, then spmm1 fused (edges L2-hot), writes e2 fp16
//  4. spmm2 (256t): pull SpMM from e2h -> fp32 out (nontemporal)

#define USER_NUM 60000
#define ITEM_NUM 40000
#define N_NODES  100000
#define EMB      64
#define NNZ      3200000
#define OMA       0.9f   // 1 - alpha
#define BR       128     // rows per bucket
#define NB       782     // ceil(100000/128)
#define TILE     4096    // edges per scatter block
#define CAPB     4480    // padded slots per bucket (mean 4096, +6 sigma)

typedef float f32x4 __attribute__((ext_vector_type(4)));

// ---- 1) fp32 split ego -> flat fp16 table; init bucket cursors ----------
__global__ __launch_bounds__(256) void conv_init(const float* __restrict__ ue,
                                                 const float* __restrict__ ie,
                                                 __half* __restrict__ dst,
                                                 int* __restrict__ bcursor) {
    int t = blockIdx.x * 256 + threadIdx.x;       // 8 floats per thread
    if (t < NB) bcursor[t] = t * CAPB;
    const int total8 = N_NODES * EMB / 8;         // 800,000
    if (t >= total8) return;
    size_t f0 = (size_t)t * 8;
    const size_t usz = (size_t)USER_NUM * EMB;    // 3,840,000 (mult of 8)
    const float4* s4 = (f0 < usz) ? (const float4*)(ue + f0)
                                  : (const float4*)(ie + (f0 - usz));
    float4 x = s4[0], y = s4[1];
    union { float4 f4; __half2 h2[4]; } o;
    o.h2[0] = __floats2half2_rn(x.x, x.y);
    o.h2[1] = __floats2half2_rn(x.z, x.w);
    o.h2[2] = __floats2half2_rn(y.x, y.y);
    o.h2[3] = __floats2half2_rn(y.z, y.w);
    ((float4*)dst)[t] = o.f4;
}

// ---- 2) single-pass bucket scatter into padded slots (512 threads) ------
// entry = (col | row_local<<17, val*0.9)
__global__ __launch_bounds__(512) void bucket_scatter(const int* __restrict__ rows,
                                                      const int* __restrict__ cols,
                                                      const float* __restrict__ vals,
                                                      int* __restrict__ bcursor,
                                                      int2* __restrict__ ebuf) {
    __shared__ int bins[NB + 1];           // hist, then exclusive offsets
    __shared__ int lcur[NB];               // binning cursors, then global bases
    __shared__ int wsum[8];
    __shared__ int2 stage[TILE];
    __shared__ unsigned short sbk[TILE];   // bucket id of each staged entry
    int t = threadIdx.x;
    int lane = t & 63, w = t >> 6;           // 8 waves
    for (int b = t; b <= NB; b += 512) bins[b] = 0;
    __syncthreads();

    // load edges, histogram into bins (8 edges/thread)
    int e0 = blockIdx.x * TILE;
    int mybk[8], mypk[8];
    float myv[8];
#pragma unroll
    for (int j = 0; j < 8; ++j) {
        int i = e0 + t + 512 * j;
        mybk[j] = -1;
        if (i < NNZ) {
            int r = rows[i], c = cols[i];
            myv[j]  = vals[i] * OMA;
            mybk[j] = r >> 7;
            mypk[j] = c | ((r & 127) << 17);
            atomicAdd(&bins[mybk[j]], 1);
        }
    }
    __syncthreads();

    // register scan: 2 bins/thread, wave shfl scan + cross-wave combine
    int b0 = t * 2;
    int r0 = (b0     < NB) ? bins[b0]     : 0;
    int r1 = (b0 + 1 < NB) ? bins[b0 + 1] : 0;
    int s = r0 + r1;
    int incl = s;
#pragma unroll
    for (int off = 1; off < 64; off <<= 1) {
        int v = __shfl_up(incl, off, 64);
        if (lane >= off) incl += v;
    }
    if (lane == 63) wsum[w] = incl;
    __syncthreads();
    int prefix = 0;
#pragma unroll
    for (int i = 0; i < 8; ++i) if (i < w) prefix += wsum[i];
    int excl = prefix + incl - s;
    if (b0     < NB) { bins[b0]     = excl; lcur[b0]     = excl; excl += r0; }
    if (b0 + 1 < NB) { bins[b0 + 1] = excl; lcur[b0 + 1] = excl; }
    if (t == 511) bins[NB] = prefix + incl;   // total valid edges this tile
    __syncthreads();

    // bin into stage (bucket-sorted order), record bucket id
#pragma unroll
    for (int j = 0; j < 8; ++j) {
        if (mybk[j] >= 0) {
            int p = atomicAdd(&lcur[mybk[j]], 1);
            stage[p] = make_int2(mypk[j], __float_as_int(myv[j]));
            sbk[p] = (unsigned short)mybk[j];
        }
    }
    __syncthreads();

    // Phase A: reserve global runs; lcur[b] := global_base - local_start
    for (int b = t; b < NB; b += 512) {
        int st = bins[b], en = bins[b + 1];
        int cnt = en - st;
        if (cnt > 0) lcur[b] = atomicAdd(&bcursor[b], cnt) - st;
    }
    __syncthreads();

    // Phase B: lane-parallel coalesced flush, direct bucket lookup
    int total = bins[NB];
    for (int i = t; i < total; i += 512) {
        int bk = sbk[i];
        ebuf[(size_t)(lcur[bk] + i)] = stage[i];
    }
}

// ---- 3) per-bucket sort + fused spmm1 (512 threads) ---------------------
__global__ __launch_bounds__(512) void sort_spmm1(const int* __restrict__ bcursor,
                                                  int2* __restrict__ ebuf,
                                                  int* __restrict__ row_start,
                                                  int* __restrict__ row_end,
                                                  const __half* __restrict__ ego_h,
                                                  const float* __restrict__ ue,
                                                  const float* __restrict__ ie,
                                                  __half* __restrict__ e2h) {
    __shared__ int2 stage[CAPB];
    __shared__ int rhist[BR], rofs[BR], rcur[BR];
    int bk = blockIdx.x, t = threadIdx.x;
    int s = bk * CAPB;
    int cnt = min(bcursor[bk] - s, CAPB);

    if (t < BR) rhist[t] = 0;
    __syncthreads();
    for (int i = t; i < cnt; i += 512) {
        int2 v = ebuf[(size_t)(s + i)];
        stage[i] = v;
        atomicAdd(&rhist[(v.x >> 17) & 127], 1);
    }
    __syncthreads();
    if (t < 64) {   // wave-0 shfl scan over 128 bins (2 per lane)
        int h0 = rhist[2 * t], h1 = rhist[2 * t + 1];
        int pair = h0 + h1;
        int incl = pair;
#pragma unroll
        for (int off = 1; off < 64; off <<= 1) {
            int v = __shfl_up(incl, off, 64);
            if (t >= off) incl += v;
        }
        int base = incl - pair;
        rofs[2 * t]     = base;      rcur[2 * t]     = base;
        rofs[2 * t + 1] = base + h0; rcur[2 * t + 1] = base + h0;
    }
    __syncthreads();
    if (t < BR) {
        int r = (bk << 7) + t;
        if (r < N_NODES) {
            row_start[r] = s + rofs[t];
            row_end[r]   = s + rofs[t] + rhist[t];
        }
    }
    // write row-sorted edges back (L2-local region)
    for (int i = t; i < cnt; i += 512) {
        int2 v = stage[i];
        int p = atomicAdd(&rcur[(v.x >> 17) & 127], 1);
        ebuf[(size_t)(s + p)] = v;
    }
    __syncthreads();   // sorted edges visible block-wide

    // fused spmm1: 32 groups x 16 lanes; each group does 4 rows
    int lane  = t & 15;
    int qbase = (t & 63) & ~15;
    int g = t >> 4;                         // 0..31
    const float2* srcv = (const float2*)ego_h;
#pragma unroll
    for (int rr = 0; rr < 4; ++rr) {
        int rl = (g << 2) | rr;             // 0..127
        int r  = (bk << 7) + rl;
        if (r >= N_NODES) break;
        const float* egop = (r < USER_NUM) ? (ue + (size_t)r * EMB)
                                           : (ie + (size_t)(r - USER_NUM) * EMB);
        float4 acc = ((const float4*)egop)[lane];
        int ss = s + rofs[rl];
        int ee = ss + rhist[rl];
        int2 cv = (ss + lane < ee) ? ebuf[(size_t)(ss + lane)] : make_int2(0, 0);
        for (int k = ss; k < ee; k += 16) {
            int idxn = k + 16 + lane;
            int2 nv = (idxn < ee) ? ebuf[(size_t)idxn] : make_int2(0, 0);
#pragma unroll
            for (int j = 0; j < 16; ++j) {
                int   cj = __shfl(cv.x, qbase + j, 64) & 0x1FFFF;
                float vj = __int_as_float(__shfl(cv.y, qbase + j, 64));
                union { float2 f2; __half2 h2[2]; } u;
                u.f2 = srcv[(size_t)cj * 16 + lane];
                float2 a = __half22float2(u.h2[0]);
                float2 b = __half22float2(u.h2[1]);
                acc.x += vj * a.x; acc.y += vj * a.y;
                acc.z += vj * b.x; acc.w += vj * b.y;
            }
            cv = nv;
        }
        union { float2 f2; __half2 h2[2]; } o;
        o.h2[0] = __floats2half2_rn(acc.x, acc.y);
        o.h2[1] = __floats2half2_rn(acc.z, acc.w);
        ((float2*)e2h)[(size_t)r * 16 + lane] = o.f2;
    }
}

// ---- 4) spmm2: pull from e2h, fp32 nontemporal out ----------------------
__global__ __launch_bounds__(256) void spmm2(const int* __restrict__ row_start,
                                             const int* __restrict__ row_end,
                                             const int2* __restrict__ colval,
                                             const __half* __restrict__ src,
                                             const float* __restrict__ ue,
                                             const float* __restrict__ ie,
                                             float* __restrict__ outb) {
    int tid = blockIdx.x * 256 + threadIdx.x;
    int r = tid >> 4;
    if (r >= N_NODES) return;
    int lane  = threadIdx.x & 15;
    int qbase = (threadIdx.x & 63) & ~15;

    const float* egop = (r < USER_NUM) ? (ue + (size_t)r * EMB)
                                       : (ie + (size_t)(r - USER_NUM) * EMB);
    float4 acc = ((const float4*)egop)[lane];
    const float2* srcv = (const float2*)src;
    int s = row_start[r], e = row_end[r];

    int2 cv = (s + lane < e) ? colval[(size_t)(s + lane)] : make_int2(0, 0);
    for (int k = s; k < e; k += 16) {
        int idxn = k + 16 + lane;
        int2 nv = (idxn < e) ? colval[(size_t)idxn] : make_int2(0, 0);
#pragma unroll
        for (int j = 0; j < 16; ++j) {
            int   cj = __shfl(cv.x, qbase + j, 64) & 0x1FFFF;
            float vj = __int_as_float(__shfl(cv.y, qbase + j, 64));
            union { float2 f2; __half2 h2[2]; } u;
            u.f2 = srcv[(size_t)cj * 16 + lane];
            float2 a = __half22float2(u.h2[0]);
            float2 b = __half22float2(u.h2[1]);
            acc.x += vj * a.x; acc.y += vj * a.y;
            acc.z += vj * b.x; acc.w += vj * b.y;
        }
        cv = nv;
    }
    f32x4 av = { acc.x, acc.y, acc.z, acc.w };
    __builtin_nontemporal_store(av, &((f32x4*)outb)[(size_t)r * 16 + lane]);
}

// ---- launch -------------------------------------------------------------
extern "C" void kernel_launch(void* const* d_in, const int* in_sizes, int n_in,
                              void* d_out, int out_size, void* d_ws, size_t ws_size,
                              hipStream_t stream) {
    const int*   rows = (const int*)d_in[0];
    const int*   cols = (const int*)d_in[1];
    const float* vals = (const float*)d_in[2];
    const float* ue   = (const float*)d_in[3];
    const float* ie   = (const float*)d_in[4];
    float* out = (float*)d_out;

    char* ws = (char*)d_ws;
    __half* ego_h    = (__half*)ws;                   // 12,800,000 B
    __half* e2h      = (__half*)(ws + 12800000);      // 12,800,000 B
    int2*   ebuf     = (int2*)(ws + 25600000);        // 782*4480*8 = 28,026,880 B
    int*    row_s    = (int*)(ws + 53626880);         // 400,000 B
    int*    row_e    = (int*)(ws + 54026880);         // 400,000 B
    int*    bcursor  = (int*)(ws + 54426880);         // 3,128 B

    const int convBlocks = (N_NODES * EMB / 8 + 255) / 256;  // 3125
    conv_init<<<convBlocks, 256, 0, stream>>>(ue, ie, ego_h, bcursor);

    const int tiles = (NNZ + TILE - 1) / TILE;        // 782
    bucket_scatter<<<tiles, 512, 0, stream>>>(rows, cols, vals, bcursor, ebuf);
    sort_spmm1<<<NB, 512, 0, stream>>>(bcursor, ebuf, row_s, row_e, ego_h, ue, ie, e2h);

    const int spmmBlocks = (N_NODES * 16 + 255) / 256;  // 6250
    spmm2<<<spmmBlocks, 256, 0, stream>>>(row_s, row_e, ebuf, e2h, ue, ie, out);
}

// Round 7
// 264.296 us; speedup vs baseline: 10.8762x; 1.0575x over previous
//
#include <hip/hip_runtime.h>
#include <hip/hip_fp16.h>

// APPNP encoder: e3 = ego + 0.9*A@(ego + 0.9*A@ego).
// R15 = R14 with the coverage bug fixed: sort_spmm1's register-held edge
// load now uses 9 slots/thread (512*9=4608 >= CAPB=4480); R14's 8 slots
// covered only 4096 and dropped edges in half the buckets (absmax 3e-2).
// R14 content kept: conv fused into scatter; bcursor via hipMemsetAsync
// (base-relative); sort_spmm1 keeps sorted edges in LDS (kills the 25.6MB
// global edge re-read) and writes the sorted copy back coalesced for spmm2;
// spmm2 uses nontemporal edge-stream loads.
// Empirical law (R8/R9/R12/R13): a pass of 3.2M random 128B row gathers
// takes ~86us (~37G req/s) regardless of occupancy, L2 hit rate, or shape.
//  1. bucket_scatter (512t): conv slice + single-pass scatter into buckets
//  2. sort_spmm1 (512t): reg-held counting sort -> LDS-resident edges,
//     coalesced ebuf writeback, fused spmm1 -> e2 fp16
//  3. spmm2 (256t): pull SpMM from e2h -> fp32 out (nontemporal)

#define USER_NUM 60000
#define ITEM_NUM 40000
#define N_NODES  100000
#define EMB      64
#define NNZ      3200000
#define OMA       0.9f   // 1 - alpha
#define BR       128     // rows per bucket
#define NB       782     // ceil(100000/128)
#define TILE     4096    // edges per scatter block
#define CAPB     4480    // padded slots per bucket (mean 4096, +6 sigma)
#define EPT      9       // edge slots per thread in sort: 512*9=4608 >= CAPB

typedef float f32x4 __attribute__((ext_vector_type(4)));

// ---- 1) conv slice + single-pass bucket scatter (512 threads) -----------
// entry = (col | row_local<<17, val*0.9)
__global__ __launch_bounds__(512) void bucket_scatter(const int* __restrict__ rows,
                                                      const int* __restrict__ cols,
                                                      const float* __restrict__ vals,
                                                      const float* __restrict__ ue,
                                                      const float* __restrict__ ie,
                                                      __half* __restrict__ ego_h,
                                                      int* __restrict__ bcursor,
                                                      int2* __restrict__ ebuf) {
    __shared__ int bins[NB + 1];           // hist, then exclusive offsets
    __shared__ int lcur[NB];               // binning cursors, then global bases
    __shared__ int wsum[8];
    __shared__ int2 stage[TILE];
    __shared__ unsigned short sbk[TILE];   // bucket id of each staged entry
    int t = threadIdx.x;
    int lane = t & 63, w = t >> 6;           // 8 waves

    // fused conv: this block's 1024 8-float units of the fp16 ego table
    {
        const int total8 = N_NODES * EMB / 8;          // 800,000
        const size_t usz = (size_t)USER_NUM * EMB;     // 3,840,000
        int u0 = blockIdx.x * 1024;
#pragma unroll
        for (int q = 0; q < 2; ++q) {
            int u = u0 + t + 512 * q;
            if (u < total8) {
                size_t f0 = (size_t)u * 8;
                const float4* s4 = (f0 < usz) ? (const float4*)(ue + f0)
                                              : (const float4*)(ie + (f0 - usz));
                float4 x = s4[0], y = s4[1];
                union { float4 f4; __half2 h2[4]; } o;
                o.h2[0] = __floats2half2_rn(x.x, x.y);
                o.h2[1] = __floats2half2_rn(x.z, x.w);
                o.h2[2] = __floats2half2_rn(y.x, y.y);
                o.h2[3] = __floats2half2_rn(y.z, y.w);
                ((float4*)ego_h)[u] = o.f4;
            }
        }
    }

    for (int b = t; b <= NB; b += 512) bins[b] = 0;
    __syncthreads();

    // load edges, histogram into bins (8 edges/thread; TILE=4096=512*8)
    int e0 = blockIdx.x * TILE;
    int mybk[8], mypk[8];
    float myv[8];
#pragma unroll
    for (int j = 0; j < 8; ++j) {
        int i = e0 + t + 512 * j;
        mybk[j] = -1;
        if (i < NNZ) {
            int r = rows[i], c = cols[i];
            myv[j]  = vals[i] * OMA;
            mybk[j] = r >> 7;
            mypk[j] = c | ((r & 127) << 17);
            atomicAdd(&bins[mybk[j]], 1);
        }
    }
    __syncthreads();

    // register scan: 2 bins/thread, wave shfl scan + cross-wave combine
    int b0 = t * 2;
    int r0 = (b0     < NB) ? bins[b0]     : 0;
    int r1 = (b0 + 1 < NB) ? bins[b0 + 1] : 0;
    int s = r0 + r1;
    int incl = s;
#pragma unroll
    for (int off = 1; off < 64; off <<= 1) {
        int v = __shfl_up(incl, off, 64);
        if (lane >= off) incl += v;
    }
    if (lane == 63) wsum[w] = incl;
    __syncthreads();
    int prefix = 0;
#pragma unroll
    for (int i = 0; i < 8; ++i) if (i < w) prefix += wsum[i];
    int excl = prefix + incl - s;
    if (b0     < NB) { bins[b0]     = excl; lcur[b0]     = excl; excl += r0; }
    if (b0 + 1 < NB) { bins[b0 + 1] = excl; lcur[b0 + 1] = excl; }
    if (t == 511) bins[NB] = prefix + incl;   // total valid edges this tile
    __syncthreads();

    // bin into stage (bucket-sorted order), record bucket id
#pragma unroll
    for (int j = 0; j < 8; ++j) {
        if (mybk[j] >= 0) {
            int p = atomicAdd(&lcur[mybk[j]], 1);
            stage[p] = make_int2(mypk[j], __float_as_int(myv[j]));
            sbk[p] = (unsigned short)mybk[j];
        }
    }
    __syncthreads();

    // Phase A: reserve global runs; lcur[b] := bucket_base + run_base - st
    for (int b = t; b < NB; b += 512) {
        int st = bins[b], en = bins[b + 1];
        int c = en - st;
        if (c > 0) lcur[b] = b * CAPB + atomicAdd(&bcursor[b], c) - st;
    }
    __syncthreads();

    // Phase B: lane-parallel coalesced flush, direct bucket lookup
    int total = bins[NB];
    for (int i = t; i < total; i += 512) {
        int bk = sbk[i];
        ebuf[(size_t)(lcur[bk] + i)] = stage[i];
    }
}

// ---- 2) reg-held counting sort + LDS-resident fused spmm1 (512t) --------
__global__ __launch_bounds__(512) void sort_spmm1(const int* __restrict__ bcursor,
                                                  int2* __restrict__ ebuf,
                                                  int* __restrict__ row_start,
                                                  int* __restrict__ row_end,
                                                  const __half* __restrict__ ego_h,
                                                  const float* __restrict__ ue,
                                                  const float* __restrict__ ie,
                                                  __half* __restrict__ e2h) {
    __shared__ int2 stage[CAPB];
    __shared__ int rhist[BR], rofs[BR], rcur[BR];
    int bk = blockIdx.x, t = threadIdx.x;
    int s = bk * CAPB;
    int cnt = min(bcursor[bk], CAPB);

    if (t < BR) rhist[t] = 0;
    __syncthreads();

    // (a) edges -> registers (EPT slots: full CAPB coverage), histogram rows
    int2 ev[EPT]; int erow[EPT];
#pragma unroll
    for (int j = 0; j < EPT; ++j) {
        int i = t + 512 * j;
        erow[j] = -1;
        if (i < cnt) {
            ev[j] = ebuf[(size_t)(s + i)];
            erow[j] = (ev[j].x >> 17) & 127;
            atomicAdd(&rhist[erow[j]], 1);
        }
    }
    __syncthreads();
    // (b) wave-0 shfl scan over 128 bins (2 per lane)
    if (t < 64) {
        int h0 = rhist[2 * t], h1 = rhist[2 * t + 1];
        int pair = h0 + h1;
        int incl = pair;
#pragma unroll
        for (int off = 1; off < 64; off <<= 1) {
            int v = __shfl_up(incl, off, 64);
            if (t >= off) incl += v;
        }
        int base = incl - pair;
        rofs[2 * t]     = base;      rcur[2 * t]     = base;
        rofs[2 * t + 1] = base + h0; rcur[2 * t + 1] = base + h0;
    }
    __syncthreads();
    if (t < BR) {
        int r = (bk << 7) + t;
        if (r < N_NODES) {
            row_start[r] = s + rofs[t];
            row_end[r]   = s + rofs[t] + rhist[t];
        }
    }
    // (c) place sorted into LDS stage
#pragma unroll
    for (int j = 0; j < EPT; ++j) {
        if (erow[j] >= 0) {
            int p = atomicAdd(&rcur[erow[j]], 1);
            stage[p] = ev[j];
        }
    }
    __syncthreads();
    // (d) coalesced sorted writeback for spmm2 (no re-read needed here)
    for (int i = t; i < cnt; i += 512) ebuf[(size_t)(s + i)] = stage[i];

    // (e) fused spmm1: 32 groups x 16 lanes; 4 rows/group; edges from LDS
    int lane  = t & 15;
    int qbase = (t & 63) & ~15;
    int g = t >> 4;                         // 0..31
    const float2* srcv = (const float2*)ego_h;
#pragma unroll
    for (int rr = 0; rr < 4; ++rr) {
        int rl = (g << 2) | rr;             // 0..127
        int r  = (bk << 7) + rl;
        if (r >= N_NODES) break;
        const float* egop = (r < USER_NUM) ? (ue + (size_t)r * EMB)
                                           : (ie + (size_t)(r - USER_NUM) * EMB);
        float4 acc = ((const float4*)egop)[lane];
        int ss = rofs[rl];
        int ee = ss + rhist[rl];
        for (int k = ss; k < ee; k += 16) {
            int idx = k + lane;
            int2 cv = (idx < ee) ? stage[idx] : make_int2(0, 0);
#pragma unroll
            for (int j = 0; j < 16; ++j) {
                int   cj = __shfl(cv.x, qbase + j, 64) & 0x1FFFF;
                float vj = __int_as_float(__shfl(cv.y, qbase + j, 64));
                union { float2 f2; __half2 h2[2]; } u;
                u.f2 = srcv[(size_t)cj * 16 + lane];
                float2 a = __half22float2(u.h2[0]);
                float2 b = __half22float2(u.h2[1]);
                acc.x += vj * a.x; acc.y += vj * a.y;
                acc.z += vj * b.x; acc.w += vj * b.y;
            }
        }
        union { float2 f2; __half2 h2[2]; } o;
        o.h2[0] = __floats2half2_rn(acc.x, acc.y);
        o.h2[1] = __floats2half2_rn(acc.z, acc.w);
        ((float2*)e2h)[(size_t)r * 16 + lane] = o.f2;
    }
}

// ---- 3) spmm2: pull from e2h, nt edge stream, fp32 nt out ---------------
__global__ __launch_bounds__(256) void spmm2(const int* __restrict__ row_start,
                                             const int* __restrict__ row_end,
                                             const int2* __restrict__ colval,
                                             const __half* __restrict__ src,
                                             const float* __restrict__ ue,
                                             const float* __restrict__ ie,
                                             float* __restrict__ outb) {
    int tid = blockIdx.x * 256 + threadIdx.x;
    int r = tid >> 4;
    if (r >= N_NODES) return;
    int lane  = threadIdx.x & 15;
    int qbase = (threadIdx.x & 63) & ~15;

    const float* egop = (r < USER_NUM) ? (ue + (size_t)r * EMB)
                                       : (ie + (size_t)(r - USER_NUM) * EMB);
    float4 acc = ((const float4*)egop)[lane];
    const float2* srcv = (const float2*)src;
    const unsigned long long* cv8 = (const unsigned long long*)colval;
    int s = row_start[r], e = row_end[r];

    unsigned long long cv = 0;
    if (s + lane < e) cv = __builtin_nontemporal_load(&cv8[(size_t)(s + lane)]);
    for (int k = s; k < e; k += 16) {
        int idxn = k + 16 + lane;
        unsigned long long nv = 0;
        if (idxn < e) nv = __builtin_nontemporal_load(&cv8[(size_t)idxn]);
        int cx = (int)(cv & 0xFFFFFFFFull), cy = (int)(cv >> 32);
#pragma unroll
        for (int j = 0; j < 16; ++j) {
            int   cj = __shfl(cx, qbase + j, 64) & 0x1FFFF;
            float vj = __int_as_float(__shfl(cy, qbase + j, 64));
            union { float2 f2; __half2 h2[2]; } u;
            u.f2 = srcv[(size_t)cj * 16 + lane];
            float2 a = __half22float2(u.h2[0]);
            float2 b = __half22float2(u.h2[1]);
            acc.x += vj * a.x; acc.y += vj * a.y;
            acc.z += vj * b.x; acc.w += vj * b.y;
        }
        cv = nv;
    }
    f32x4 av = { acc.x, acc.y, acc.z, acc.w };
    __builtin_nontemporal_store(av, &((f32x4*)outb)[(size_t)r * 16 + lane]);
}

// ---- launch -------------------------------------------------------------
extern "C" void kernel_launch(void* const* d_in, const int* in_sizes, int n_in,
                              void* d_out, int out_size, void* d_ws, size_t ws_size,
                              hipStream_t stream) {
    const int*   rows = (const int*)d_in[0];
    const int*   cols = (const int*)d_in[1];
    const float* vals = (const float*)d_in[2];
    const float* ue   = (const float*)d_in[3];
    const float* ie   = (const float*)d_in[4];
    float* out = (float*)d_out;

    char* ws = (char*)d_ws;
    __half* ego_h    = (__half*)ws;                   // 12,800,000 B
    __half* e2h      = (__half*)(ws + 12800000);      // 12,800,000 B
    int2*   ebuf     = (int2*)(ws + 25600000);        // 782*4480*8 = 28,026,880 B
    int*    row_s    = (int*)(ws + 53626880);         // 400,000 B
    int*    row_e    = (int*)(ws + 54026880);         // 400,000 B
    int*    bcursor  = (int*)(ws + 54426880);         // 3,128 B

    hipMemsetAsync(bcursor, 0, NB * sizeof(int), stream);

    const int tiles = (NNZ + TILE - 1) / TILE;        // 782
    bucket_scatter<<<tiles, 512, 0, stream>>>(rows, cols, vals, ue, ie, ego_h,
                                              bcursor, ebuf);
    sort_spmm1<<<NB, 512, 0, stream>>>(bcursor, ebuf, row_s, row_e, ego_h, ue, ie, e2h);

    const int spmmBlocks = (N_NODES * 16 + 255) / 256;  // 6250
    spmm2<<<spmmBlocks, 256, 0, stream>>>(row_s, row_e, ebuf, e2h, ue, ie, out);
}